// Round 1
// baseline (371.810 us; speedup 1.0000x reference)
//
#include <hip/hip_runtime.h>

#define NB 16
#define NG 1600
#define NM 64
#define ND 2048

// ---------------------------------------------------------------------------
// Kernel 1: per-(b,g) variance over D=2048, ddof=1. One wave per (b,g).
// Lane reads 8 float4 (32 floats), coalesced 1 KiB/instr across the wave.
// Double accumulators: (ss - s*s/N) cancellation is the only numeric hazard;
// kernel is HBM-bound so f64 ALU is free.
// ---------------------------------------------------------------------------
__global__ __launch_bounds__(256) void var_kernel(const float* __restrict__ atten,
                                                  float* __restrict__ v) {
    const int wave = threadIdx.x >> 6;
    const int lane = threadIdx.x & 63;
    const int bg = blockIdx.x * 4 + wave;          // < 25600 (grid = 6400)
    const float4* p = (const float4*)(atten + (size_t)bg * ND);
    double s = 0.0, ss = 0.0;
#pragma unroll
    for (int k = 0; k < 8; ++k) {
        float4 f = p[lane + 64 * k];
        double x0 = f.x, x1 = f.y, x2 = f.z, x3 = f.w;
        s += (x0 + x1) + (x2 + x3);
        ss += (x0 * x0 + x1 * x1) + (x2 * x2 + x3 * x3);
    }
#pragma unroll
    for (int off = 32; off > 0; off >>= 1) {
        s += __shfl_down(s, off, 64);
        ss += __shfl_down(ss, off, 64);
    }
    if (lane == 0)
        v[bg] = (float)((ss - s * s / (double)ND) / (double)(ND - 1));
}

// ---------------------------------------------------------------------------
// Kernel 2: per-batch assignment + segmented mean partials. One block/batch.
// The reference's scan simplifies: all_free is redundant (all_free==true
// implies flag==-1 for every masked point), so the per-point update is
//   if (mask) flag = (flag==-1) ? m : -1;
// and mask = inside | (g == argmin_dist(center_m)) depends only on
// precomputed per-box data -> each grid point scans the 64 boxes
// independently, no per-step block reductions.
// ---------------------------------------------------------------------------
__global__ __launch_bounds__(256) void assign_kernel(const float* __restrict__ gt,
                                                     const float* __restrict__ v,
                                                     float* __restrict__ partials) {
    __shared__ float s_cx[NM], s_cy[NM];
    __shared__ float s_kx[NM][4], s_ky[NM][4];
    __shared__ int   s_gmin[NM];
    __shared__ float s_rd[256];
    __shared__ int   s_ri[256];
    __shared__ float s_sum[NM];
    __shared__ int   s_cnt[NM];

    const int b = blockIdx.x;
    const int t = threadIdx.x;
    const float* bb = gt + (size_t)b * NM * 7;

    // Phase 1: per-box derived data (threads 0..63)
    if (t < NM) {
        const float cx = bb[t * 7 + 0], cy = bb[t * 7 + 1];
        const float l = bb[t * 7 + 3], w = bb[t * 7 + 4];
        const float ang = bb[t * 7 + 6];
        float rl = 2.56f / l; rl = fminf(fmaxf(rl, 1.0f), 6.0f);
        float rw = 2.56f / w; rw = fminf(fmaxf(rw, 1.0f), 6.0f);
        const float el = l * rl, ew = w * rw;
        const float c = cosf(ang), s = sinf(ang);
        // cn order: (-.5,-.5), (-.5,.5), (.5,.5), (.5,-.5); corner = R*(dims*cn)+ctr
        const float cnx[4] = {-0.5f, -0.5f, 0.5f, 0.5f};
        const float cny[4] = {-0.5f, 0.5f, 0.5f, -0.5f};
#pragma unroll
        for (int k = 0; k < 4; ++k) {
            const float lx = el * cnx[k], ly = ew * cny[k];
            s_kx[t][k] = c * lx - s * ly + cx;
            s_ky[t][k] = s * lx + c * ly + cy;
        }
        s_cx[t] = cx; s_cy[t] = cy;
        s_sum[t] = 0.0f; s_cnt[t] = 0;
    }
    __syncthreads();

    // Phase 2: per-box argmin of dist(grid, center). 4 threads/box, 400 pts
    // each (10 rows x 40). Strict '<' ascending => first-min (jnp.argmin tie
    // semantics).
    {
        const int m = t >> 2, q = t & 3;
        const float cx = s_cx[m], cy = s_cy[m];
        float best = 3.4e38f; int bidx = 0;
        for (int r = 0; r < 10; ++r) {
            const int hi = q * 10 + r;
            const float py = (hi + 0.5f) / 40.0f * 102.4f - 51.2f;
            const float dy = py - cy;
            const float dy2 = dy * dy;
            for (int wi = 0; wi < 40; ++wi) {
                const float px = (wi + 0.5f) / 40.0f * 102.4f - 51.2f;
                const float dx = px - cx;
                const float d = dx * dx + dy2;
                if (d < best) { best = d; bidx = hi * 40 + wi; }
            }
        }
        s_rd[t] = best; s_ri[t] = bidx;
    }
    __syncthreads();
    if (t < NM) {
        float best = s_rd[t * 4]; int bidx = s_ri[t * 4];
#pragma unroll
        for (int q = 1; q < 4; ++q) {
            if (s_rd[t * 4 + q] < best) { best = s_rd[t * 4 + q]; bidx = s_ri[t * 4 + q]; }
        }
        s_gmin[t] = bidx;
    }
    __syncthreads();

    // Phase 3: per-point flag scan over 64 boxes (7 points/thread, strided)
    int   flg[7];
    float ppx[7], ppy[7];
#pragma unroll
    for (int k = 0; k < 7; ++k) {
        const int g = t + 256 * k;
        flg[k] = -1;
        if (g < NG) {
            const int wi = g % 40, hi = g / 40;
            ppx[k] = (wi + 0.5f) / 40.0f * 102.4f - 51.2f;
            ppy[k] = (hi + 0.5f) / 40.0f * 102.4f - 51.2f;
        }
    }
    for (int m = 0; m < NM; ++m) {
        const float kx0 = s_kx[m][0], kx1 = s_kx[m][1], kx2 = s_kx[m][2], kx3 = s_kx[m][3];
        const float ky0 = s_ky[m][0], ky1 = s_ky[m][1], ky2 = s_ky[m][2], ky3 = s_ky[m][3];
        const float e0x = kx1 - kx0, e0y = ky1 - ky0;
        const float e1x = kx2 - kx1, e1y = ky2 - ky1;
        const float e2x = kx3 - kx2, e2y = ky3 - ky2;
        const float e3x = kx0 - kx3, e3y = ky0 - ky3;
        const int gm = s_gmin[m];
#pragma unroll
        for (int k = 0; k < 7; ++k) {
            const int g = t + 256 * k;
            if (g < NG) {
                const float px = ppx[k], py = ppy[k];
                const float c0 = e0x * (py - ky0) - e0y * (px - kx0);
                const float c1 = e1x * (py - ky1) - e1y * (px - kx1);
                const float c2 = e2x * (py - ky2) - e2y * (px - kx2);
                const float c3 = e3x * (py - ky3) - e3y * (px - kx3);
                const bool inside =
                    (c0 >= 0.f && c1 >= 0.f && c2 >= 0.f && c3 >= 0.f) ||
                    (c0 <= 0.f && c1 <= 0.f && c2 <= 0.f && c3 <= 0.f);
                if (inside || g == gm) flg[k] = (flg[k] == -1) ? m : -1;
            }
        }
    }

    // Phase 4: segmented sums/counts via LDS atomics
    const float* vb = v + (size_t)b * NG;
#pragma unroll
    for (int k = 0; k < 7; ++k) {
        const int g = t + 256 * k;
        if (g < NG && flg[k] >= 0) {
            atomicAdd(&s_sum[flg[k]], vb[g]);
            atomicAdd(&s_cnt[flg[k]], 1);
        }
    }
    __syncthreads();

    // Phase 5: per-batch partial (wave 0 = threads 0..63, one lane per box)
    if (t < NM) {
        float mean = (s_cnt[t] > 0) ? (s_sum[t] / (float)s_cnt[t]) : 0.0f;
        float pos  = (s_cnt[t] > 0) ? 1.0f : 0.0f;
#pragma unroll
        for (int off = 32; off > 0; off >>= 1) {
            mean += __shfl_down(mean, off, 64);
            pos  += __shfl_down(pos, off, 64);
        }
        if (t == 0) { partials[2 * b] = mean; partials[2 * b + 1] = pos; }
    }
}

// ---------------------------------------------------------------------------
// Kernel 3: combine 16 per-batch partials -> scalar
// ---------------------------------------------------------------------------
__global__ void final_kernel(const float* __restrict__ partials, float* __restrict__ out) {
    float S = 0.0f, P = 0.0f;
    for (int b = 0; b < NB; ++b) { S += partials[2 * b]; P += partials[2 * b + 1]; }
    out[0] = -S / fmaxf(P, 1.0f);
}

extern "C" void kernel_launch(void* const* d_in, const int* in_sizes, int n_in,
                              void* d_out, int out_size, void* d_ws, size_t ws_size,
                              hipStream_t stream) {
    const float* atten = (const float*)d_in[0];   // (16, 1600, 2048) f32
    const float* gt    = (const float*)d_in[1];   // (16, 64, 7) f32
    float* out = (float*)d_out;                   // scalar f32

    // ws layout: v[25600] floats, then partials[32] floats (~100.1 KB total)
    float* v = (float*)d_ws;
    float* partials = v + NB * NG;

    hipLaunchKernelGGL(var_kernel,   dim3(NB * NG / 4), dim3(256), 0, stream, atten, v);
    hipLaunchKernelGGL(assign_kernel, dim3(NB),          dim3(256), 0, stream, gt, v, partials);
    hipLaunchKernelGGL(final_kernel,  dim3(1),           dim3(1),   0, stream, partials, out);
}

// Round 3
// 303.051 us; speedup vs baseline: 1.2269x; 1.2269x over previous
//
#include <hip/hip_runtime.h>

#define NB 16
#define NG 1600
#define NM 64
#define ND 2048

typedef float floatx4 __attribute__((ext_vector_type(4)));

// ws layout: v[NB*NG] floats, then acc[4]: acc[0]=S, acc[1]=P, ((int*)acc)[2]=ticket
// ---------------------------------------------------------------------------
// Kernel 1: per-(b,g) variance over D=2048, ddof=1. One wave per (b,g).
// Nontemporal float4 loads (pure streaming, no reuse). Double accumulators
// guard the (ss - s^2/N) cancellation; kernel is HBM-bound so f64 is free.
// Block 0 thread 0 also zero-inits the global accumulators for kernel 2
// (d_ws is re-poisoned 0xAA before every call; same-stream ordering makes
// the zeros visible to the next dispatch).
// ---------------------------------------------------------------------------
__global__ __launch_bounds__(256) void var_kernel(const float* __restrict__ atten,
                                                  float* __restrict__ v,
                                                  float* __restrict__ acc) {
    if (blockIdx.x == 0 && threadIdx.x == 0) {
        acc[0] = 0.0f; acc[1] = 0.0f; ((int*)acc)[2] = 0;
    }
    const int wave = threadIdx.x >> 6;
    const int lane = threadIdx.x & 63;
    const int bg = blockIdx.x * 4 + wave;          // < 25600 (grid = 6400)
    const floatx4* p = (const floatx4*)(atten + (size_t)bg * ND);
    double s = 0.0, ss = 0.0;
#pragma unroll
    for (int k = 0; k < 8; ++k) {
        floatx4 f = __builtin_nontemporal_load(p + lane + 64 * k);
        double x0 = f.x, x1 = f.y, x2 = f.z, x3 = f.w;
        s += (x0 + x1) + (x2 + x3);
        ss += (x0 * x0 + x1 * x1) + (x2 * x2 + x3 * x3);
    }
#pragma unroll
    for (int off = 32; off > 0; off >>= 1) {
        s += __shfl_down(s, off, 64);
        ss += __shfl_down(ss, off, 64);
    }
    if (lane == 0)
        v[bg] = (float)((ss - s * s / (double)ND) / (double)(ND - 1));
}

// ---------------------------------------------------------------------------
// Kernel 2: per-batch assignment + segmented means + fused final reduce.
// One block per batch, 512 threads.
//
// Scan simplification: the reference's all_free term is redundant
// (all_free==true implies flag==-1 for every masked point), so per point:
//   if (mask) flag = (flag==-1) ? m : -1;
// mask = inside_poly | (g == argmin_dist(center_m)); both depend only on
// precomputed per-box data -> fully parallel over grid points.
//
// Analytic argmin: dist^2 = dx^2 + dy^2 is separable over the regular grid;
// flattened row-major first-tie == (first-tie argmin over h) * 40 +
// (first-tie argmin over w). 3 clamped candidates per axis, distances
// evaluated with the same f32 expressions as the brute-force reference.
//
// Final: per-block (batch) partial -> device-scope atomics; last block
// (ticket counter) combines and writes the scalar output. Accumulator reads
// go through atomicAdd(p, 0.0f) to stay in the coherent atomic path
// (per-XCD L2s are not cross-coherent for plain loads).
// ---------------------------------------------------------------------------
__device__ __forceinline__ int axis_argmin(float c) {
    // grid coord: p(i) = (i+0.5)/40*102.4 - 51.2, i in [0,40)
    float u = (c + 51.2f) / 2.56f - 0.5f;
    int i0 = (int)floorf(u) - 1;
    if (i0 < 0) i0 = 0;
    if (i0 > 37) i0 = 37;
    int best_i = i0;
    float best_d = 3.4e38f;
#pragma unroll
    for (int k = 0; k < 3; ++k) {
        int i = i0 + k;
        float p = (i + 0.5f) / 40.0f * 102.4f - 51.2f;
        float d = p - c;
        float d2 = d * d;
        if (d2 < best_d) { best_d = d2; best_i = i; }   // strict < ascending => first-tie
    }
    return best_i;
}

__global__ __launch_bounds__(512) void assign_kernel(const float* __restrict__ gt,
                                                     const float* __restrict__ v,
                                                     float* __restrict__ acc,
                                                     float* __restrict__ out) {
    __shared__ float s_kx[NM][4], s_ky[NM][4];
    __shared__ int   s_gmin[NM];
    __shared__ float s_sum[NM];
    __shared__ int   s_cnt[NM];

    const int b = blockIdx.x;
    const int t = threadIdx.x;
    const float* bb = gt + (size_t)b * NM * 7;

    // Phase 1: per-box corners + analytic argmin (threads 0..63)
    if (t < NM) {
        const float cx = bb[t * 7 + 0], cy = bb[t * 7 + 1];
        const float l = bb[t * 7 + 3], w = bb[t * 7 + 4];
        const float ang = bb[t * 7 + 6];
        float rl = 2.56f / l; rl = fminf(fmaxf(rl, 1.0f), 6.0f);
        float rw = 2.56f / w; rw = fminf(fmaxf(rw, 1.0f), 6.0f);
        const float el = l * rl, ew = w * rw;
        const float c = cosf(ang), s = sinf(ang);
        const float cnx[4] = {-0.5f, -0.5f, 0.5f, 0.5f};
        const float cny[4] = {-0.5f, 0.5f, 0.5f, -0.5f};
#pragma unroll
        for (int k = 0; k < 4; ++k) {
            const float lx = el * cnx[k], ly = ew * cny[k];
            s_kx[t][k] = c * lx - s * ly + cx;
            s_ky[t][k] = s * lx + c * ly + cy;
        }
        s_gmin[t] = axis_argmin(cy) * 40 + axis_argmin(cx);
        s_sum[t] = 0.0f; s_cnt[t] = 0;
    }
    __syncthreads();

    // Phase 2: per-point flag scan over 64 boxes (<=4 points/thread, strided)
    int   flg[4];
    float ppx[4], ppy[4];
#pragma unroll
    for (int k = 0; k < 4; ++k) {
        const int g = t + 512 * k;
        flg[k] = -1;
        if (g < NG) {
            const int wi = g % 40, hi = g / 40;
            ppx[k] = (wi + 0.5f) / 40.0f * 102.4f - 51.2f;
            ppy[k] = (hi + 0.5f) / 40.0f * 102.4f - 51.2f;
        }
    }
    for (int m = 0; m < NM; ++m) {
        const float kx0 = s_kx[m][0], kx1 = s_kx[m][1], kx2 = s_kx[m][2], kx3 = s_kx[m][3];
        const float ky0 = s_ky[m][0], ky1 = s_ky[m][1], ky2 = s_ky[m][2], ky3 = s_ky[m][3];
        const float e0x = kx1 - kx0, e0y = ky1 - ky0;
        const float e1x = kx2 - kx1, e1y = ky2 - ky1;
        const float e2x = kx3 - kx2, e2y = ky3 - ky2;
        const float e3x = kx0 - kx3, e3y = ky0 - ky3;
        const int gm = s_gmin[m];
#pragma unroll
        for (int k = 0; k < 4; ++k) {
            const int g = t + 512 * k;
            if (g < NG) {
                const float px = ppx[k], py = ppy[k];
                const float c0 = e0x * (py - ky0) - e0y * (px - kx0);
                const float c1 = e1x * (py - ky1) - e1y * (px - kx1);
                const float c2 = e2x * (py - ky2) - e2y * (px - kx2);
                const float c3 = e3x * (py - ky3) - e3y * (px - kx3);
                const bool inside =
                    (c0 >= 0.f && c1 >= 0.f && c2 >= 0.f && c3 >= 0.f) ||
                    (c0 <= 0.f && c1 <= 0.f && c2 <= 0.f && c3 <= 0.f);
                if (inside || g == gm) flg[k] = (flg[k] == -1) ? m : -1;
            }
        }
    }

    // Phase 3: segmented sums/counts via LDS atomics
    const float* vb = v + (size_t)b * NG;
#pragma unroll
    for (int k = 0; k < 4; ++k) {
        const int g = t + 512 * k;
        if (g < NG && flg[k] >= 0) {
            atomicAdd(&s_sum[flg[k]], vb[g]);
            atomicAdd(&s_cnt[flg[k]], 1);
        }
    }
    __syncthreads();

    // Phase 4: per-batch partial (threads 0..63, one lane per box) + fused
    // final combine in the last-arriving block.
    if (t < NM) {
        float mean = (s_cnt[t] > 0) ? (s_sum[t] / (float)s_cnt[t]) : 0.0f;
        float pos  = (s_cnt[t] > 0) ? 1.0f : 0.0f;
#pragma unroll
        for (int off = 32; off > 0; off >>= 1) {
            mean += __shfl_down(mean, off, 64);
            pos  += __shfl_down(pos, off, 64);
        }
        if (t == 0) {
            atomicAdd(&acc[0], mean);
            atomicAdd(&acc[1], pos);
            __threadfence();
            int old = atomicAdd((int*)acc + 2, 1);
            if (old == NB - 1) {
                float S = atomicAdd(&acc[0], 0.0f);   // coherent read path
                float P = atomicAdd(&acc[1], 0.0f);
                out[0] = -S / fmaxf(P, 1.0f);
            }
        }
    }
}

extern "C" void kernel_launch(void* const* d_in, const int* in_sizes, int n_in,
                              void* d_out, int out_size, void* d_ws, size_t ws_size,
                              hipStream_t stream) {
    const float* atten = (const float*)d_in[0];   // (16, 1600, 2048) f32
    const float* gt    = (const float*)d_in[1];   // (16, 64, 7) f32
    float* out = (float*)d_out;                   // scalar f32

    float* v   = (float*)d_ws;
    float* acc = v + NB * NG;                     // S, P, ticket

    hipLaunchKernelGGL(var_kernel,    dim3(NB * NG / 4), dim3(256), 0, stream, atten, v, acc);
    hipLaunchKernelGGL(assign_kernel, dim3(NB),          dim3(512), 0, stream, gt, v, acc, out);
}

// Round 4
// 288.144 us; speedup vs baseline: 1.2904x; 1.0517x over previous
//
#include <hip/hip_runtime.h>

#define NB 16
#define NG 1600
#define NM 64
#define ND 2048

typedef float floatx4 __attribute__((ext_vector_type(4)));

// ws layout: v[NB*NG] f32 | gsum[NB*NM] f32 | gcnt[NB*NM] i32 | ticket i32
// ---------------------------------------------------------------------------
// Kernel 1: per-(b,g) variance over D=2048, ddof=1. One wave per (b,g).
// Nontemporal float4 streaming loads; double accumulators guard the
// (ss - s^2/N) cancellation (HBM-bound, f64 ALU free). Block 0 also zeroes
// the gsum/gcnt/ticket region for kernel 2 — safe because those cells are
// only touched by the subsequent dispatch (stream order).
// ---------------------------------------------------------------------------
__global__ __launch_bounds__(256) void var_kernel(const float* __restrict__ atten,
                                                  float* __restrict__ v,
                                                  float* __restrict__ gsum,
                                                  int* __restrict__ gcnt,
                                                  int* __restrict__ ticket) {
    if (blockIdx.x == 0) {
        for (int i = threadIdx.x; i < NB * NM; i += 256) { gsum[i] = 0.0f; gcnt[i] = 0; }
        if (threadIdx.x == 0) *ticket = 0;
    }
    const int wave = threadIdx.x >> 6;
    const int lane = threadIdx.x & 63;
    const int bg = blockIdx.x * 4 + wave;          // < 25600 (grid = 6400)
    const floatx4* p = (const floatx4*)(atten + (size_t)bg * ND);
    double s = 0.0, ss = 0.0;
#pragma unroll
    for (int k = 0; k < 8; ++k) {
        floatx4 f = __builtin_nontemporal_load(p + lane + 64 * k);
        double x0 = f.x, x1 = f.y, x2 = f.z, x3 = f.w;
        s += (x0 + x1) + (x2 + x3);
        ss += (x0 * x0 + x1 * x1) + (x2 * x2 + x3 * x3);
    }
#pragma unroll
    for (int off = 32; off > 0; off >>= 1) {
        s += __shfl_down(s, off, 64);
        ss += __shfl_down(ss, off, 64);
    }
    if (lane == 0)
        v[bg] = (float)((ss - s * s / (double)ND) / (double)(ND - 1));
}

// ---------------------------------------------------------------------------
// Kernel 2: assignment + segmented means + fused final reduce.
// Grid (NB, 5) x 320 threads: 1 grid point per thread (80 blocks vs 16 —
// the flag scan is the VALU hot loop; 5x more CUs cuts it ~3x).
//
// Scan simplification (proved R1): the reference's all_free term is
// redundant, so per point: if (mask) flag = (flag==-1) ? m : -1;
// mask = inside_poly | (g == argmin_dist(center_m)) — fully parallel.
//
// Analytic argmin: dist^2 separable over the regular grid; row-major
// first-tie == first-tie per axis; 3 clamped candidates, f32 expressions
// identical to the brute-force reference.
//
// Cross-block combine: LDS partials -> device-scope atomicAdd into
// gsum/gcnt; ticket elects the last of 80 blocks to compute means and the
// scalar output (threadfence + agent-scope atomic loads for coherent
// cross-XCD reads).
// ---------------------------------------------------------------------------
__device__ __forceinline__ int axis_argmin(float c) {
    float u = (c + 51.2f) / 2.56f - 0.5f;
    int i0 = (int)floorf(u) - 1;
    if (i0 < 0) i0 = 0;
    if (i0 > 37) i0 = 37;
    int best_i = i0;
    float best_d = 3.4e38f;
#pragma unroll
    for (int k = 0; k < 3; ++k) {
        int i = i0 + k;
        float p = (i + 0.5f) / 40.0f * 102.4f - 51.2f;
        float d = p - c;
        float d2 = d * d;
        if (d2 < best_d) { best_d = d2; best_i = i; }   // strict < ascending => first-tie
    }
    return best_i;
}

__global__ __launch_bounds__(320) void assign_kernel(const float* __restrict__ gt,
                                                     const float* __restrict__ v,
                                                     float* __restrict__ gsum,
                                                     int* __restrict__ gcnt,
                                                     int* __restrict__ ticket,
                                                     float* __restrict__ out) {
    __shared__ float s_kx[NM][4], s_ky[NM][4];
    __shared__ int   s_gmin[NM];
    __shared__ float s_sum[NM];
    __shared__ int   s_cnt[NM];
    __shared__ int   s_last;
    __shared__ float s_redS[5], s_redP[5];

    const int b = blockIdx.x;
    const int q = blockIdx.y;
    const int t = threadIdx.x;
    const int g = q * 320 + t;                     // < 1600
    const float* bb = gt + (size_t)b * NM * 7;

    // Phase 1: per-box corners + analytic argmin (threads 0..63)
    if (t < NM) {
        const float cx = bb[t * 7 + 0], cy = bb[t * 7 + 1];
        const float l = bb[t * 7 + 3], w = bb[t * 7 + 4];
        const float ang = bb[t * 7 + 6];
        float rl = 2.56f / l; rl = fminf(fmaxf(rl, 1.0f), 6.0f);
        float rw = 2.56f / w; rw = fminf(fmaxf(rw, 1.0f), 6.0f);
        const float el = l * rl, ew = w * rw;
        const float c = cosf(ang), s = sinf(ang);
        const float cnx[4] = {-0.5f, -0.5f, 0.5f, 0.5f};
        const float cny[4] = {-0.5f, 0.5f, 0.5f, -0.5f};
#pragma unroll
        for (int k = 0; k < 4; ++k) {
            const float lx = el * cnx[k], ly = ew * cny[k];
            s_kx[t][k] = c * lx - s * ly + cx;
            s_ky[t][k] = s * lx + c * ly + cy;
        }
        s_gmin[t] = axis_argmin(cy) * 40 + axis_argmin(cx);
        s_sum[t] = 0.0f; s_cnt[t] = 0;
    }
    __syncthreads();

    // Phase 2: flag scan over 64 boxes, one point per thread
    const int wi = g % 40, hi = g / 40;
    const float px = (wi + 0.5f) / 40.0f * 102.4f - 51.2f;
    const float py = (hi + 0.5f) / 40.0f * 102.4f - 51.2f;
    int flg = -1;
    for (int m = 0; m < NM; ++m) {
        const float kx0 = s_kx[m][0], kx1 = s_kx[m][1], kx2 = s_kx[m][2], kx3 = s_kx[m][3];
        const float ky0 = s_ky[m][0], ky1 = s_ky[m][1], ky2 = s_ky[m][2], ky3 = s_ky[m][3];
        const float c0 = (kx1 - kx0) * (py - ky0) - (ky1 - ky0) * (px - kx0);
        const float c1 = (kx2 - kx1) * (py - ky1) - (ky2 - ky1) * (px - kx1);
        const float c2 = (kx3 - kx2) * (py - ky2) - (ky3 - ky2) * (px - kx2);
        const float c3 = (kx0 - kx3) * (py - ky3) - (ky0 - ky3) * (px - kx3);
        const bool inside =
            (c0 >= 0.f && c1 >= 0.f && c2 >= 0.f && c3 >= 0.f) ||
            (c0 <= 0.f && c1 <= 0.f && c2 <= 0.f && c3 <= 0.f);
        if (inside || g == s_gmin[m]) flg = (flg == -1) ? m : -1;
    }

    // Phase 3: block-local segmented sums via LDS atomics
    if (flg >= 0) {
        atomicAdd(&s_sum[flg], v[(size_t)b * NG + g]);
        atomicAdd(&s_cnt[flg], 1);
    }
    __syncthreads();

    // Phase 4: block partials -> global atomics; ticket elects final block
    if (t < NM && s_cnt[t] > 0) {
        atomicAdd(&gsum[b * NM + t], s_sum[t]);
        atomicAdd(&gcnt[b * NM + t], s_cnt[t]);
    }
    __threadfence();
    __syncthreads();
    if (t == 0) s_last = atomicAdd(ticket, 1);
    __syncthreads();

    if (s_last == NB * 5 - 1) {
        // Phase 5: final combine (all 80 blocks' atomics are globally visible:
        // they fenced before incrementing the ticket we just observed).
        __threadfence();
        float S = 0.0f, P = 0.0f;
        for (int i = t; i < NB * NM; i += 320) {
            int   c = __hip_atomic_load(&gcnt[i], __ATOMIC_RELAXED, __HIP_MEMORY_SCOPE_AGENT);
            float s = __hip_atomic_load(&gsum[i], __ATOMIC_RELAXED, __HIP_MEMORY_SCOPE_AGENT);
            if (c > 0) { S += s / (float)c; P += 1.0f; }
        }
#pragma unroll
        for (int off = 32; off > 0; off >>= 1) {
            S += __shfl_down(S, off, 64);
            P += __shfl_down(P, off, 64);
        }
        const int wv = t >> 6, ln = t & 63;
        if (ln == 0) { s_redS[wv] = S; s_redP[wv] = P; }
        __syncthreads();
        if (t == 0) {
            float ST = 0.0f, PT = 0.0f;
#pragma unroll
            for (int w = 0; w < 5; ++w) { ST += s_redS[w]; PT += s_redP[w]; }
            out[0] = -ST / fmaxf(PT, 1.0f);
        }
    }
}

extern "C" void kernel_launch(void* const* d_in, const int* in_sizes, int n_in,
                              void* d_out, int out_size, void* d_ws, size_t ws_size,
                              hipStream_t stream) {
    const float* atten = (const float*)d_in[0];   // (16, 1600, 2048) f32
    const float* gt    = (const float*)d_in[1];   // (16, 64, 7) f32
    float* out = (float*)d_out;                   // scalar f32

    float* v      = (float*)d_ws;
    float* gsum   = v + NB * NG;
    int*   gcnt   = (int*)(gsum + NB * NM);
    int*   ticket = gcnt + NB * NM;

    hipLaunchKernelGGL(var_kernel,    dim3(NB * NG / 4), dim3(256), 0, stream,
                       atten, v, gsum, gcnt, ticket);
    hipLaunchKernelGGL(assign_kernel, dim3(NB, 5),       dim3(320), 0, stream,
                       gt, v, gsum, gcnt, ticket, out);
}